// Round 11
// baseline (1562.270 us; speedup 1.0000x reference)
//
#include <hip/hip_runtime.h>
#include <hip/hip_bf16.h>

// ---------------- problem constants ----------------
#define Nn 8000      // nodes
#define Ee 32000     // edges
#define Bb 64        // graphs
#define Dembed 200
#define Ttok 20
#define Mp 8192      // padded node count
#define K1 4096      // padded 4000 (layer-1 in dim)
#define K1L 4032     // K-loop trim: first mult of 64 >= 4000
#define K2 6144      // padded 6000 (layer-1/2 out dim)
#define K2L 6016     // K-loop trim: first mult of 64 >= 6000
#define L1p 3072     // padded 3000
#define LCHUNK 256   // split-K chunk for lin1
#define NCH 24       // ceil(6000/256)

// GEMM tile geometry (256^2, 8 waves x 128x64, single-barrier tile loop)
#define GBM 256
#define GBN 256
#define GBK 64
#define ABUF (GBM * GBK)          // 16384 els (A region per buffer)
#define BUFE (2 * ABUF)           // 32768 els per buffer (A+B)

#define LRELU(v) ((v) > 0.f ? (v) : 0.01f * (v))

typedef __attribute__((ext_vector_type(4))) float f32x4;
typedef __attribute__((ext_vector_type(16))) float f32x16;
typedef __attribute__((ext_vector_type(8))) short s16x8;
typedef __attribute__((ext_vector_type(4))) short s16x4;

#define GLL16(gp, lp) __builtin_amdgcn_global_load_lds( \
    (const __attribute__((address_space(1))) void*)(gp), \
    (__attribute__((address_space(3))) void*)(lp), 16, 0, 0)

__device__ __forceinline__ float b2f(short s) {
    union { unsigned u; float f; } c;
    c.u = ((unsigned)(unsigned short)s) << 16;
    return c.f;
}
__device__ __forceinline__ short f2b(float f) {
    __hip_bfloat16 h = __float2bfloat16(f);  // RNE
    return __builtin_bit_cast(short, h);
}

// ---------------- embedding gather ----------------
__global__ __launch_bounds__(256)
void k_gather(const int* __restrict__ x, const float* __restrict__ emb,
              short* __restrict__ h0, int Wp)
{
    const int i = blockIdx.x;
    __shared__ int tok[Ttok];
    if (threadIdx.x < Ttok) tok[threadIdx.x] = x[i * Ttok + threadIdx.x];
    __syncthreads();
    for (int c = threadIdx.x; c < Wp; c += 256) {
        float v = 0.f;
        if (c < Ttok * Dembed) {
            int t = c / Dembed;
            int d = c - t * Dembed;
            v = emb[(long)tok[t] * Dembed + d];
        }
        h0[(long)i * Wp + c] = f2b(v);
    }
}

// ---------------- degree / dinv / CSR build ----------------
__global__ void k_deg(const int* __restrict__ dst, int* __restrict__ indeg) {
    int e = blockIdx.x * 256 + threadIdx.x;
    if (e < Ee) atomicAdd(&indeg[dst[e]], 1);
}

// single-block exclusive scan of indeg -> rowptr, plus dinv (fused)
__global__ __launch_bounds__(1024)
void k_scan(const int* __restrict__ indeg, int* __restrict__ rowptr,
            float* __restrict__ dinv, int n)
{
    __shared__ int sums[1024];
    const int t = threadIdx.x;
    const int base = t * 8;
    int loc[8];
    int s = 0;
#pragma unroll
    for (int j = 0; j < 8; ++j) {
        int v = (base + j < n) ? indeg[base + j] : 0;
        loc[j] = s; s += v;
    }
    sums[t] = s;
    __syncthreads();
    for (int off = 1; off < 1024; off <<= 1) {
        int v = sums[t];
        int add = (t >= off) ? sums[t - off] : 0;
        __syncthreads();
        sums[t] = v + add;
        __syncthreads();
    }
    const int prev = (t == 0) ? 0 : sums[t - 1];
#pragma unroll
    for (int j = 0; j < 8; ++j)
        if (base + j < n) {
            rowptr[base + j] = prev + loc[j];
            dinv[base + j] = rsqrtf((float)indeg[base + j] + 1.0f);
        }
    if (t == 1023) rowptr[n] = sums[1023];
}

__global__ void k_fill(const int* __restrict__ src, const int* __restrict__ dst,
                       const int* __restrict__ rowptr, int* __restrict__ fillc,
                       int* __restrict__ csr) {
    int e = blockIdx.x * 256 + threadIdx.x;
    if (e < Ee) {
        int d = dst[e];
        int pos = rowptr[d] + atomicAdd(&fillc[d], 1);
        csr[pos] = src[e];
    }
}

// ---------------- normalized aggregation (LDS-preloaded neighbor lists) ----------------
template<int NG>
__global__ __launch_bounds__(256)
void k_agg(const short* __restrict__ Hin, short* __restrict__ Hout,
           const float* __restrict__ dinv, const int* __restrict__ rowptr,
           const int* __restrict__ csr, int Wp)
{
    const int i = blockIdx.x;
    const int tid = threadIdx.x;
    __shared__ int   s_idx[64];
    __shared__ float s_w[64];
    const float di = dinv[i];
    const float wself = di * di;
    const long rowi = (long)i * Wp;
    float acc[NG * 8];
#pragma unroll
    for (int gI = 0; gI < NG; ++gI) {
        s16x8 v = *(const s16x8*)(Hin + rowi + gI * 2048 + tid * 8);
#pragma unroll
        for (int j = 0; j < 8; ++j) acc[gI * 8 + j] = wself * b2f(v[j]);
    }
    const int e0 = rowptr[i], e1 = rowptr[i + 1];
    for (int eb = e0; eb < e1; eb += 64) {
        const int cnt = min(64, e1 - eb);
        __syncthreads();
        if (tid < cnt) {
            int s = csr[eb + tid];
            s_idx[tid] = s;
            s_w[tid] = dinv[s] * di;
        }
        __syncthreads();
        for (int e = 0; e < cnt; ++e) {
            const long rows = (long)s_idx[e] * Wp;
            const float w = s_w[e];
#pragma unroll
            for (int gI = 0; gI < NG; ++gI) {
                s16x8 v = *(const s16x8*)(Hin + rows + gI * 2048 + tid * 8);
#pragma unroll
                for (int j = 0; j < 8; ++j) acc[gI * 8 + j] += w * b2f(v[j]);
            }
        }
    }
#pragma unroll
    for (int gI = 0; gI < NG; ++gI) {
        s16x8 o;
#pragma unroll
        for (int j = 0; j < 8; ++j) o[j] = f2b(acc[gI * 8 + j]);
        *(s16x8*)(Hout + rowi + gI * 2048 + tid * 8) = o;
    }
}

// ---------------- transpose + fp32->bf16 (vectorized 8B stores) ----------------
__global__ __launch_bounds__(256)
void k_transpose(const float* __restrict__ In, short* __restrict__ Out,
                 int K, int N, int Kp, int Np)
{
    __shared__ float tile[32][33];
    const int k0 = blockIdx.x * 32;
    const int n0 = blockIdx.y * 32;
    const int tid = threadIdx.x;
    const int ln = tid & 31, lk = tid >> 5;   // load: n fast (coalesced)
#pragma unroll
    for (int kk = lk; kk < 32; kk += 8) {
        int k = k0 + kk, n = n0 + ln;
        tile[kk][ln] = (k < K && n < N) ? In[(long)k * N + n] : 0.f;
    }
    __syncthreads();
    const int kq = tid & 7, nn = tid >> 3;    // store: 4 consecutive k per thread
    s16x4 o;
#pragma unroll
    for (int j = 0; j < 4; ++j) o[j] = f2b(tile[kq * 4 + j][nn]);
    *(s16x4*)(&Out[(long)(n0 + nn) * Kp + k0 + kq * 4]) = o;
}

// ---------------- 256^2 pipelined GEMM, 32x32x16 MFMA: C = A*Bt^T + bias, leaky ----------------
// R7 single-barrier structure; MFMA shape swapped 16x16x32 -> 32x32x16 (rate 2382 vs
// 2075 TF, half the instruction count). Wave tile 128x64 = 4x2 tiles of 32x32, each
// accumulated over 4 k-slices of 16. Fragment layouts: A/B in: row(col)=lane&31,
// k=(lane>>5)*8+j; C/D: col=lane&31, row=(r&3)+8*(r>>2)+4*(lane>>5) [m74/m101].
// LDS swizzle + staging identical to R7 (16B-aligned k offsets, XOR-compatible).
__global__ __launch_bounds__(512, 2)
void k_gemm32(const short* __restrict__ A, const short* __restrict__ Bt,
              short* __restrict__ C, const float* __restrict__ bias,
              int K, int Kloop, int Np, int Nreal, int nbx)
{
    __shared__ short lds[2 * BUFE];   // 128 KiB

    const int tid  = threadIdx.x;
    const int lane = tid & 63;
    const int wid  = tid >> 6;
    const int wm   = wid >> 2;   // 0..1
    const int wn   = wid & 3;    // 0..3

    // T1: XCD-aware block swizzle (gridDim.x % 8 == 0)
    const int cpx = (int)gridDim.x >> 3;
    const int bid = (int)blockIdx.x;
    const int swz = (bid & 7) * cpx + (bid >> 3);
    const int bx = swz % nbx;          // N tile
    const int by = swz / nbx;          // M tile

    // ---- staging (per thread), pre-swizzled global source, linear LDS dest ----
    const int rq = tid >> 3;                                // 0..63 (row within chunk)
    const int kq = ((tid & 7) << 3) ^ ((rq & 7) << 3);      // swizzled k source
    const short* Abase = A  + ((long)by * GBM + rq) * K + kq;
    const short* Bbase = Bt + ((long)bx * GBN + rq) * K + kq;

#define ST2(bb, t2, base, ldoff, c0_, c1_) do { \
    const short* g0_ = (base) + (long)((c0_) * 64) * K + (long)(t2) * GBK; \
    const short* g1_ = (base) + (long)((c1_) * 64) * K + (long)(t2) * GBK; \
    GLL16(g0_, lds + (bb) * BUFE + (ldoff) + (c0_) * 4096 + tid * 8); \
    GLL16(g1_, lds + (bb) * BUFE + (ldoff) + (c1_) * 4096 + tid * 8); \
  } while (0)

    // ---- fragment read addresses (swizzled), 32x32x16 layout ----
    const int fr32 = lane & 31;                 // row/col within 32-tile
    const int kg8  = (lane >> 5) << 3;          // 0 or 8 (k sub-offset)
    const int xm32 = (fr32 & 7) << 3;
    int ck32[4];
#pragma unroll
    for (int ks = 0; ks < 4; ++ks) ck32[ks] = (ks * 16 + kg8) ^ xm32;
    const int aoff = (wm * 128 + fr32) * 64;        // + m32*2048 + ck
    const int boff = ABUF + (wn * 64 + fr32) * 64;  // + n32*2048 + ck

    f32x16 acc[4][2] = {};                      // [m32][n32]
    s16x8 av[2][4], av2[2][4], bv[2][4];        // [m32 or n32][ks]

    const int NT = Kloop >> 6;

    // ---- prologue: stage tile 0 into buf0 ----
    ST2(0, 0, Bbase, ABUF, 0, 1);
    ST2(0, 0, Bbase, ABUF, 2, 3);
    ST2(0, 0, Abase, 0,    0, 2);
    ST2(0, 0, Abase, 0,    1, 3);
    asm volatile("s_waitcnt vmcnt(0)" ::: "memory");
    __builtin_amdgcn_s_barrier();

    int buf = 0;
    for (int t = 0; t < NT; ++t) {
        const short* lb = lds + buf * BUFE;
        const int nb = buf ^ 1;
        const bool pf = (t + 1 < NT);

        // B reads (8): bv[n32][ks]
#pragma unroll
        for (int n = 0; n < 2; ++n)
#pragma unroll
            for (int ks = 0; ks < 4; ++ks)
                bv[n][ks] = *(const s16x8*)(lb + boff + n * 2048 + ck32[ks]);
        // A m32 0-1 reads (8)
#pragma unroll
        for (int m = 0; m < 2; ++m)
#pragma unroll
            for (int ks = 0; ks < 4; ++ks)
                av[m][ks] = *(const s16x8*)(lb + aoff + m * 2048 + ck32[ks]);
        if (pf) ST2(nb, t + 1, Bbase, ABUF, 0, 1);
        // A m32 2-3 reads (8) — issued before MFMA G1 so they land under it
#pragma unroll
        for (int m = 0; m < 2; ++m)
#pragma unroll
            for (int ks = 0; ks < 4; ++ks)
                av2[m][ks] = *(const s16x8*)(lb + aoff + (2 + m) * 2048 + ck32[ks]);
        if (pf) ST2(nb, t + 1, Bbase, ABUF, 2, 3);
        // MFMA G1: m32 0-1 (16 MFMA); ks outer -> 4 independent accs per ks
        __builtin_amdgcn_s_setprio(1);
#pragma unroll
        for (int ks = 0; ks < 4; ++ks)
#pragma unroll
            for (int m = 0; m < 2; ++m)
#pragma unroll
                for (int n = 0; n < 2; ++n)
                    acc[m][n] = __builtin_amdgcn_mfma_f32_32x32x16_bf16(av[m][ks], bv[n][ks], acc[m][n], 0, 0, 0);
        __builtin_amdgcn_s_setprio(0);
        if (pf) ST2(nb, t + 1, Abase, 0, 0, 2);
        // MFMA G2: m32 2-3 (16 MFMA)
        __builtin_amdgcn_s_setprio(1);
#pragma unroll
        for (int ks = 0; ks < 4; ++ks)
#pragma unroll
            for (int m = 0; m < 2; ++m)
#pragma unroll
                for (int n = 0; n < 2; ++n)
                    acc[2 + m][n] = __builtin_amdgcn_mfma_f32_32x32x16_bf16(av2[m][ks], bv[n][ks], acc[2 + m][n], 0, 0, 0);
        __builtin_amdgcn_s_setprio(0);
        if (pf) ST2(nb, t + 1, Abase, 0, 1, 3);

        // boundary: drain (GLLs issued ~full tile ago) + single barrier
        asm volatile("s_waitcnt vmcnt(0)" ::: "memory");
        __builtin_amdgcn_s_barrier();
        buf = nb;
    }

    // ---- epilogue: bias + leaky + bf16 store (32x32 C/D layout) ----
    const int r4 = (lane >> 5) << 2;   // +4*(lane>>5)
#pragma unroll
    for (int n = 0; n < 2; ++n) {
        const long col = (long)bx * GBN + wn * 64 + n * 32 + fr32;
        const float bvv = (col < Nreal) ? bias[col] : 0.f;
#pragma unroll
        for (int m = 0; m < 4; ++m) {
#pragma unroll
            for (int r = 0; r < 16; ++r) {
                const long row = (long)by * GBM + wm * 128 + m * 32
                               + (r & 3) + 8 * (r >> 2) + r4;
                float v = acc[m][n][r] + bvv;
                v = LRELU(v);
                C[row * Np + col] = f2b(v);
            }
        }
    }
#undef ST2
}

// ---------------- batch boundaries ----------------
__global__ void k_bptr(const int* __restrict__ batch, int* __restrict__ bptr) {
    int i = blockIdx.x * 256 + threadIdx.x;
    if (i >= Nn) return;
    int b = batch[i];
    int pb = (i == 0) ? -1 : batch[i - 1];
    for (int bb = pb + 1; bb <= b; ++bb) bptr[bb] = i;
    if (i == Nn - 1)
        for (int bb = b + 1; bb <= Bb; ++bb) bptr[bb] = Nn;
}

// ---------------- global max pool (vectorized: 8 cols/thread) ----------------
__global__ __launch_bounds__(256)
void k_pool(const short* __restrict__ h2, const int* __restrict__ bptr,
            float* __restrict__ g, int Wp) {
    const int c8 = blockIdx.x * 256 + threadIdx.x;   // group of 8 cols
    const int b = blockIdx.y;
    const short* base = h2 + (long)c8 * 8;
    float mx[8];
#pragma unroll
    for (int j = 0; j < 8; ++j) mx[j] = -INFINITY;
    const int i0 = bptr[b], i1 = bptr[b + 1];
    for (int i = i0; i < i1; ++i) {
        s16x8 v = *(const s16x8*)(base + (long)i * Wp);
#pragma unroll
        for (int j = 0; j < 8; ++j) mx[j] = fmaxf(mx[j], b2f(v[j]));
    }
#pragma unroll
    for (int j = 0; j < 8; ++j) g[(long)b * Wp + c8 * 8 + j] = mx[j];
}

// ---------------- linear1 split-K ----------------
__global__ __launch_bounds__(256)
void k_lin1_part(const float* __restrict__ g, const float* __restrict__ Wl1,
                 float* __restrict__ part) {
    __shared__ float gs[64][65];
    __shared__ float Ws[64][64];
    const int tid = threadIdx.x;
    const int jc = blockIdx.x * 64;
    const int k0 = blockIdx.y * LCHUNK;
    const int k1 = min(6000, k0 + LCHUNK);
    const int r = tid & 63;
    const int jb = (tid >> 6) * 16;
    float acc[16] = {};
    for (int kc = k0; kc < k1; kc += 64) {
#pragma unroll
        for (int p = 0; p < 16; ++p) {
            int el = p * 256 + tid;
            int rr = el >> 6, kk = el & 63;
            gs[rr][kk] = (kc + kk < k1) ? g[rr * K2 + kc + kk] : 0.f;
            Ws[rr][kk] = (kc + rr < k1 && jc + kk < 3000)
                         ? Wl1[(long)(kc + rr) * 3000 + jc + kk] : 0.f;
        }
        __syncthreads();
#pragma unroll
        for (int k = 0; k < 64; ++k) {
            float a = gs[r][k];
#pragma unroll
            for (int jj = 0; jj < 16; ++jj)
                acc[jj] += a * Ws[k][jb + jj];
        }
        __syncthreads();
    }
    float* prow = part + ((long)blockIdx.y * 64 + r) * L1p + jc + jb;
#pragma unroll
    for (int jj = 0; jj < 16; ++jj) prow[jj] = acc[jj];
}

__global__ __launch_bounds__(256)
void k_lin1_red(const float* __restrict__ part, const float* __restrict__ bl1,
                float* __restrict__ g1) {
    int idx = blockIdx.x * 256 + threadIdx.x;
    if (idx >= 64 * 3000) return;
    int r = idx / 3000;
    int c = idx - r * 3000;
    float s = bl1[c];
#pragma unroll
    for (int p = 0; p < NCH; ++p)
        s += part[((long)p * 64 + r) * L1p + c];
    g1[r * L1p + c] = LRELU(s);
}

// ---------------- linear2 ----------------
__global__ __launch_bounds__(256)
void k_lin2(const float* __restrict__ g1, const float* __restrict__ Wl2,
            const float* __restrict__ bl2, float* __restrict__ out) {
    const int r = blockIdx.x;
    const int tid = threadIdx.x;
    float a0 = 0, a1 = 0, a2 = 0, a3 = 0;
    for (int k = tid; k < 3000; k += 256) {
        float gv = g1[r * L1p + k];
        const float* w = Wl2 + (long)k * 4;
        a0 += gv * w[0]; a1 += gv * w[1]; a2 += gv * w[2]; a3 += gv * w[3];
    }
    __shared__ float red[256][4];
    red[tid][0] = a0; red[tid][1] = a1; red[tid][2] = a2; red[tid][3] = a3;
    __syncthreads();
    for (int s = 128; s > 0; s >>= 1) {
        if (tid < s) {
            red[tid][0] += red[tid + s][0]; red[tid][1] += red[tid + s][1];
            red[tid][2] += red[tid + s][2]; red[tid][3] += red[tid + s][3];
        }
        __syncthreads();
    }
    if (tid < 4) {
        float v = red[0][tid] + bl2[tid];
        out[r * 4 + tid] = LRELU(v);
    }
}

// ---------------- launch ----------------
extern "C" void kernel_launch(void* const* d_in, const int* in_sizes, int n_in,
                              void* d_out, int out_size, void* d_ws, size_t ws_size,
                              hipStream_t stream)
{
    const int*   x     = (const int*)d_in[0];
    const int*   ei    = (const int*)d_in[1];
    const int*   batch = (const int*)d_in[2];
    const float* emb   = (const float*)d_in[3];
    const float* W1    = (const float*)d_in[4];
    const float* b1    = (const float*)d_in[5];
    const float* W2    = (const float*)d_in[6];
    const float* b2    = (const float*)d_in[7];
    const float* Wl1   = (const float*)d_in[8];
    const float* bl1   = (const float*)d_in[9];
    const float* Wl2   = (const float*)d_in[10];
    const float* bl2   = (const float*)d_in[11];
    float* out = (float*)d_out;

    const int* esrc = ei;
    const int* edst = ei + Ee;

    const size_t MiB = 1ull << 20;
    char* W = (char*)d_ws;
    short* h0b  = (short*)(W + 0);          // [8192,4096] bf16, 64 MiB
    short* Ah0b = (short*)(W + 64 * MiB);   // [8192,4096] bf16, 64 MiB
    short* W2t  = (short*)(W + 96 * MiB);   // [6144,6144] bf16, 72 MiB (after GEMM1)
    short* W1t  = (short*)(W + 128 * MiB);  // [6144,4096] bf16, 48 MiB
    short* h1b  = (short*)(W + 176 * MiB);  // [8192,6144] bf16, 96 MiB
    short* Ah1b = (short*)(W + 0);          // [8192,6144] bf16, 96 MiB (after GEMM1)
    short* h2b  = h1b;                      // reuse
    float* part = (float*)(W + 0);          // [24][64][3072] f32 (after pool)
    char* S = W + 272 * MiB;
    int*   indeg  = (int*)(S);
    float* dinv   = (float*)(S + 32 * 1024);
    int*   rowptr = (int*)(S + 64 * 1024);
    int*   fillc  = (int*)(S + 96 * 1024);
    int*   csr    = (int*)(S + 128 * 1024);
    int*   bptr   = (int*)(S + 256 * 1024);
    float* g      = (float*)(S + 320 * 1024);
    float* g1     = (float*)(S + 320 * 1024 + 2 * MiB);

    hipMemsetAsync(indeg, 0, Nn * sizeof(int), stream);
    hipMemsetAsync(fillc, 0, Nn * sizeof(int), stream);

    k_gather<<<Nn, 256, 0, stream>>>(x, emb, h0b, K1);
    k_deg<<<(Ee + 255) / 256, 256, 0, stream>>>(edst, indeg);
    k_scan<<<1, 1024, 0, stream>>>(indeg, rowptr, dinv, Nn);
    k_fill<<<(Ee + 255) / 256, 256, 0, stream>>>(esrc, edst, rowptr, fillc, csr);

    const int nbx = K2 / GBN;               // 24
    const int nwg = nbx * (Mp / GBM);       // 24*32 = 768, % 8 == 0

    k_agg<2><<<Nn, 256, 0, stream>>>(h0b, Ah0b, dinv, rowptr, csr, K1);
    k_transpose<<<dim3(K1 / 32, K2 / 32), 256, 0, stream>>>(W1, W1t, 4000, 6000, K1, K2);
    k_gemm32<<<nwg, 512, 0, stream>>>(Ah0b, W1t, h1b, b1, K1, K1L, K2, 6000, nbx);

    k_transpose<<<dim3(K2 / 32, K2 / 32), 256, 0, stream>>>(W2, W2t, 6000, 6000, K2, K2);
    k_agg<3><<<Nn, 256, 0, stream>>>(h1b, Ah1b, dinv, rowptr, csr, K2);
    k_gemm32<<<nwg, 512, 0, stream>>>(Ah1b, W2t, h2b, b2, K2, K2L, K2, 6000, nbx);

    k_bptr<<<(Nn + 255) / 256, 256, 0, stream>>>(batch, bptr);
    k_pool<<<dim3(K2 / 2048, Bb), 256, 0, stream>>>(h2b, bptr, g, K2);
    k_lin1_part<<<dim3(L1p / 64, NCH), 256, 0, stream>>>(g, Wl1, part);
    k_lin1_red<<<(64 * 3000 + 255) / 256, 256, 0, stream>>>(part, bl1, g1);
    k_lin2<<<Bb, 256, 0, stream>>>(g1, Wl2, bl2, out);
}

// Round 12
// 1341.721 us; speedup vs baseline: 1.1644x; 1.1644x over previous
//
#include <hip/hip_runtime.h>
#include <hip/hip_bf16.h>

// ---------------- problem constants ----------------
#define Nn 8000      // nodes
#define Ee 32000     // edges
#define Bb 64        // graphs
#define Dembed 200
#define Ttok 20
#define Mp 8192      // padded node count
#define K1 4096      // padded 4000 (layer-1 in dim)
#define K1L 4032     // K-loop trim: first mult of 64 >= 4000
#define K2 6144      // padded 6000 (layer-1/2 out dim)
#define K2L 6016     // K-loop trim: first mult of 64 >= 6000
#define L1p 3072     // padded 3000
#define LCHUNK 256   // split-K chunk for lin1
#define NCH 24       // ceil(6000/256)

// GEMM tile geometry (256^2, 8 waves x 128x64, single-barrier tile loop) — R7/R10 proven
#define GBM 256
#define GBN 256
#define GBK 64
#define ABUF (GBM * GBK)          // 16384 els (A region per buffer)
#define BUFE (2 * ABUF)           // 32768 els per buffer (A+B)

#define LRELU(v) ((v) > 0.f ? (v) : 0.01f * (v))

typedef __attribute__((ext_vector_type(4))) float f32x4;
typedef __attribute__((ext_vector_type(8))) short s16x8;
typedef __attribute__((ext_vector_type(4))) short s16x4;

#define GLL16(gp, lp) __builtin_amdgcn_global_load_lds( \
    (const __attribute__((address_space(1))) void*)(gp), \
    (__attribute__((address_space(3))) void*)(lp), 16, 0, 0)

__device__ __forceinline__ float b2f(short s) {
    union { unsigned u; float f; } c;
    c.u = ((unsigned)(unsigned short)s) << 16;
    return c.f;
}
__device__ __forceinline__ short f2b(float f) {
    __hip_bfloat16 h = __float2bfloat16(f);  // RNE
    return __builtin_bit_cast(short, h);
}

// ---------------- embedding gather ----------------
__global__ __launch_bounds__(256)
void k_gather(const int* __restrict__ x, const float* __restrict__ emb,
              short* __restrict__ h0, int Wp)
{
    const int i = blockIdx.x;
    __shared__ int tok[Ttok];
    if (threadIdx.x < Ttok) tok[threadIdx.x] = x[i * Ttok + threadIdx.x];
    __syncthreads();
    for (int c = threadIdx.x; c < Wp; c += 256) {
        float v = 0.f;
        if (c < Ttok * Dembed) {
            int t = c / Dembed;
            int d = c - t * Dembed;
            v = emb[(long)tok[t] * Dembed + d];
        }
        h0[(long)i * Wp + c] = f2b(v);
    }
}

// ---------------- degree / dinv / CSR build ----------------
__global__ void k_deg(const int* __restrict__ dst, int* __restrict__ indeg) {
    int e = blockIdx.x * 256 + threadIdx.x;
    if (e < Ee) atomicAdd(&indeg[dst[e]], 1);
}

// single-block exclusive scan of indeg -> rowptr, plus dinv (fused)
__global__ __launch_bounds__(1024)
void k_scan(const int* __restrict__ indeg, int* __restrict__ rowptr,
            float* __restrict__ dinv, int n)
{
    __shared__ int sums[1024];
    const int t = threadIdx.x;
    const int base = t * 8;
    int loc[8];
    int s = 0;
#pragma unroll
    for (int j = 0; j < 8; ++j) {
        int v = (base + j < n) ? indeg[base + j] : 0;
        loc[j] = s; s += v;
    }
    sums[t] = s;
    __syncthreads();
    for (int off = 1; off < 1024; off <<= 1) {
        int v = sums[t];
        int add = (t >= off) ? sums[t - off] : 0;
        __syncthreads();
        sums[t] = v + add;
        __syncthreads();
    }
    const int prev = (t == 0) ? 0 : sums[t - 1];
#pragma unroll
    for (int j = 0; j < 8; ++j)
        if (base + j < n) {
            rowptr[base + j] = prev + loc[j];
            dinv[base + j] = rsqrtf((float)indeg[base + j] + 1.0f);
        }
    if (t == 1023) rowptr[n] = sums[1023];
}

__global__ void k_fill(const int* __restrict__ src, const int* __restrict__ dst,
                       const int* __restrict__ rowptr, int* __restrict__ fillc,
                       int* __restrict__ csr) {
    int e = blockIdx.x * 256 + threadIdx.x;
    if (e < Ee) {
        int d = dst[e];
        int pos = rowptr[d] + atomicAdd(&fillc[d], 1);
        csr[pos] = src[e];
    }
}

// ---------------- normalized aggregation (LDS-preloaded neighbor lists) ----------------
template<int NG>
__global__ __launch_bounds__(256)
void k_agg(const short* __restrict__ Hin, short* __restrict__ Hout,
           const float* __restrict__ dinv, const int* __restrict__ rowptr,
           const int* __restrict__ csr, int Wp)
{
    const int i = blockIdx.x;
    const int tid = threadIdx.x;
    __shared__ int   s_idx[64];
    __shared__ float s_w[64];
    const float di = dinv[i];
    const float wself = di * di;
    const long rowi = (long)i * Wp;
    float acc[NG * 8];
#pragma unroll
    for (int gI = 0; gI < NG; ++gI) {
        s16x8 v = *(const s16x8*)(Hin + rowi + gI * 2048 + tid * 8);
#pragma unroll
        for (int j = 0; j < 8; ++j) acc[gI * 8 + j] = wself * b2f(v[j]);
    }
    const int e0 = rowptr[i], e1 = rowptr[i + 1];
    for (int eb = e0; eb < e1; eb += 64) {
        const int cnt = min(64, e1 - eb);
        __syncthreads();
        if (tid < cnt) {
            int s = csr[eb + tid];
            s_idx[tid] = s;
            s_w[tid] = dinv[s] * di;
        }
        __syncthreads();
        for (int e = 0; e < cnt; ++e) {
            const long rows = (long)s_idx[e] * Wp;
            const float w = s_w[e];
#pragma unroll
            for (int gI = 0; gI < NG; ++gI) {
                s16x8 v = *(const s16x8*)(Hin + rows + gI * 2048 + tid * 8);
#pragma unroll
                for (int j = 0; j < 8; ++j) acc[gI * 8 + j] += w * b2f(v[j]);
            }
        }
    }
#pragma unroll
    for (int gI = 0; gI < NG; ++gI) {
        s16x8 o;
#pragma unroll
        for (int j = 0; j < 8; ++j) o[j] = f2b(acc[gI * 8 + j]);
        *(s16x8*)(Hout + rowi + gI * 2048 + tid * 8) = o;
    }
}

// ---------------- transpose + fp32->bf16 (vectorized 8B stores) ----------------
__global__ __launch_bounds__(256)
void k_transpose(const float* __restrict__ In, short* __restrict__ Out,
                 int K, int N, int Kp, int Np)
{
    __shared__ float tile[32][33];
    const int k0 = blockIdx.x * 32;
    const int n0 = blockIdx.y * 32;
    const int tid = threadIdx.x;
    const int ln = tid & 31, lk = tid >> 5;   // load: n fast (coalesced)
#pragma unroll
    for (int kk = lk; kk < 32; kk += 8) {
        int k = k0 + kk, n = n0 + ln;
        tile[kk][ln] = (k < K && n < N) ? In[(long)k * N + n] : 0.f;
    }
    __syncthreads();
    const int kq = tid & 7, nn = tid >> 3;    // store: 4 consecutive k per thread
    s16x4 o;
#pragma unroll
    for (int j = 0; j < 4; ++j) o[j] = f2b(tile[kq * 4 + j][nn]);
    *(s16x4*)(&Out[(long)(n0 + nn) * Kp + k0 + kq * 4]) = o;
}

// ---------------- 256^2 pipelined bf16 MFMA GEMM (R10 proven + coalesced epilogue) ----------------
// BM=BN=256 BK=64, 512 threads (8 waves, 2M x 4N), wave tile 128x64 (acc[8][4]),
// 16x16x32 MFMA (the 8-way XOR swizzle fully de-conflicts this shape; 32x32 needs
// 32-row spread and regressed — R11). SINGLE barrier per K-tile. K-loop trim skips
// all-zero padding tiles. Epilogue stores n-innermost so the 4 consecutive 32B
// segments of each row land back-to-back (kills the 2x WRITE_SIZE amplification
// seen in R10: 193 MiB vs 96 ideal from split-line read-modify-write).
__global__ __launch_bounds__(512, 2)
void k_gemm8w(const short* __restrict__ A, const short* __restrict__ Bt,
              short* __restrict__ C, const float* __restrict__ bias,
              int K, int Kloop, int Np, int Nreal, int nbx)
{
    __shared__ short lds[2 * BUFE];   // 128 KiB

    const int tid  = threadIdx.x;
    const int lane = tid & 63;
    const int wid  = tid >> 6;
    const int wm   = wid >> 2;   // 0..1
    const int wn   = wid & 3;    // 0..3

    // T1: XCD-aware block swizzle (gridDim.x % 8 == 0)
    const int cpx = (int)gridDim.x >> 3;
    const int bid = (int)blockIdx.x;
    const int swz = (bid & 7) * cpx + (bid >> 3);
    const int bx = swz % nbx;          // N tile
    const int by = swz / nbx;          // M tile

    // ---- staging (per thread), pre-swizzled global source, linear LDS dest ----
    const int rq = tid >> 3;                                // 0..63 (row within chunk)
    const int kq = ((tid & 7) << 3) ^ ((rq & 7) << 3);      // swizzled k source
    const short* Abase = A  + ((long)by * GBM + rq) * K + kq;
    const short* Bbase = Bt + ((long)bx * GBN + rq) * K + kq;

#define ST2(bb, t2, base, ldoff, c0_, c1_) do { \
    const short* g0_ = (base) + (long)((c0_) * 64) * K + (long)(t2) * GBK; \
    const short* g1_ = (base) + (long)((c1_) * 64) * K + (long)(t2) * GBK; \
    GLL16(g0_, lds + (bb) * BUFE + (ldoff) + (c0_) * 4096 + tid * 8); \
    GLL16(g1_, lds + (bb) * BUFE + (ldoff) + (c1_) * 4096 + tid * 8); \
  } while (0)

    // ---- fragment read addresses (swizzled) ----
    const int fr  = lane & 15;
    const int kb8 = (lane >> 4) << 3;          // 0,8,16,24
    const int xm  = (fr & 7) << 3;
    const int ck0 = kb8 ^ xm;                  // kk=0 column term
    const int ck1 = (32 + kb8) ^ xm;           // kk=32 column term
    const int aoff = (wm * 128 + fr) * 64;     // + m*1024 + ck
    const int boff = ABUF + (wn * 64 + fr) * 64;  // + n*1024 + ck

    f32x4 acc[8][4] = {};
    s16x8 av_a[4], av_b[4], bv1[4], bv3[4];

    const int NT = Kloop >> 6;

    // ---- prologue: stage tile 0 into buf0 ----
    ST2(0, 0, Bbase, ABUF, 0, 1);
    ST2(0, 0, Bbase, ABUF, 2, 3);
    ST2(0, 0, Abase, 0,    0, 2);
    ST2(0, 0, Abase, 0,    1, 3);
    asm volatile("s_waitcnt vmcnt(0)" ::: "memory");
    __builtin_amdgcn_s_barrier();

    int buf = 0;
    for (int t = 0; t < NT; ++t) {
        const short* lb = lds + buf * BUFE;
        const int nb = buf ^ 1;
        const bool pf = (t + 1 < NT);

        // Q1 reads (B kk0 + A m0-3 kk0)
#pragma unroll
        for (int n = 0; n < 4; ++n) bv1[n] = *(const s16x8*)(lb + boff + n * 1024 + ck0);
#pragma unroll
        for (int m = 0; m < 4; ++m) av_a[m] = *(const s16x8*)(lb + aoff + m * 1024 + ck0);
        if (pf) ST2(nb, t + 1, Bbase, ABUF, 0, 1);
        // Q2 reads (A m4-7 kk0)
#pragma unroll
        for (int m = 0; m < 4; ++m) av_b[m] = *(const s16x8*)(lb + aoff + (4 + m) * 1024 + ck0);
        // MFMA Q1
        __builtin_amdgcn_s_setprio(1);
#pragma unroll
        for (int m = 0; m < 4; ++m)
#pragma unroll
            for (int n = 0; n < 4; ++n)
                acc[m][n] = __builtin_amdgcn_mfma_f32_16x16x32_bf16(av_a[m], bv1[n], acc[m][n], 0, 0, 0);
        __builtin_amdgcn_s_setprio(0);
        if (pf) ST2(nb, t + 1, Bbase, ABUF, 2, 3);
        // Q3 reads (B kk32 + A m4-7 kk32) — av_a reused (dead after Q1)
#pragma unroll
        for (int n = 0; n < 4; ++n) bv3[n] = *(const s16x8*)(lb + boff + n * 1024 + ck1);
#pragma unroll
        for (int m = 0; m < 4; ++m) av_a[m] = *(const s16x8*)(lb + aoff + (4 + m) * 1024 + ck1);
        // MFMA Q2
        __builtin_amdgcn_s_setprio(1);
#pragma unroll
        for (int m = 0; m < 4; ++m)
#pragma unroll
            for (int n = 0; n < 4; ++n)
                acc[4 + m][n] = __builtin_amdgcn_mfma_f32_16x16x32_bf16(av_b[m], bv1[n], acc[4 + m][n], 0, 0, 0);
        __builtin_amdgcn_s_setprio(0);
        if (pf) ST2(nb, t + 1, Abase, 0, 0, 2);
        // Q4 reads (A m0-3 kk32) — av_b reused (dead after Q2)
#pragma unroll
        for (int m = 0; m < 4; ++m) av_b[m] = *(const s16x8*)(lb + aoff + m * 1024 + ck1);
        // MFMA Q3
        __builtin_amdgcn_s_setprio(1);
#pragma unroll
        for (int m = 0; m < 4; ++m)
#pragma unroll
            for (int n = 0; n < 4; ++n)
                acc[4 + m][n] = __builtin_amdgcn_mfma_f32_16x16x32_bf16(av_a[m], bv3[n], acc[4 + m][n], 0, 0, 0);
        __builtin_amdgcn_s_setprio(0);
        if (pf) ST2(nb, t + 1, Abase, 0, 1, 3);
        // MFMA Q4
        __builtin_amdgcn_s_setprio(1);
#pragma unroll
        for (int m = 0; m < 4; ++m)
#pragma unroll
            for (int n = 0; n < 4; ++n)
                acc[m][n] = __builtin_amdgcn_mfma_f32_16x16x32_bf16(av_b[m], bv3[n], acc[m][n], 0, 0, 0);
        __builtin_amdgcn_s_setprio(0);

        // boundary: drain (issued ~full tile ago) + single barrier
        asm volatile("s_waitcnt vmcnt(0)" ::: "memory");
        __builtin_amdgcn_s_barrier();
        buf = nb;
    }

    // ---- epilogue: bias + leaky + bf16 store, n-INNERMOST for line coalescing ----
    const int rr = (lane >> 4) << 2;
    long colv[4];
    float bb[4];
#pragma unroll
    for (int n = 0; n < 4; ++n) {
        colv[n] = (long)bx * GBN + wn * 64 + n * 16 + fr;
        bb[n] = (colv[n] < Nreal) ? bias[colv[n]] : 0.f;
    }
#pragma unroll
    for (int m = 0; m < 8; ++m) {
#pragma unroll
        for (int j = 0; j < 4; ++j) {
            const long rowoff = ((long)by * GBM + wm * 128 + m * 16 + rr + j) * Np;
#pragma unroll
            for (int n = 0; n < 4; ++n) {
                float v = acc[m][n][j] + bb[n];
                v = LRELU(v);
                C[rowoff + colv[n]] = f2b(v);
            }
        }
    }
#undef ST2
}

// ---------------- batch boundaries ----------------
__global__ void k_bptr(const int* __restrict__ batch, int* __restrict__ bptr) {
    int i = blockIdx.x * 256 + threadIdx.x;
    if (i >= Nn) return;
    int b = batch[i];
    int pb = (i == 0) ? -1 : batch[i - 1];
    for (int bb = pb + 1; bb <= b; ++bb) bptr[bb] = i;
    if (i == Nn - 1)
        for (int bb = b + 1; bb <= Bb; ++bb) bptr[bb] = Nn;
}

// ---------------- global max pool (vectorized: 8 cols/thread) ----------------
__global__ __launch_bounds__(256)
void k_pool(const short* __restrict__ h2, const int* __restrict__ bptr,
            float* __restrict__ g, int Wp) {
    const int c8 = blockIdx.x * 256 + threadIdx.x;   // group of 8 cols
    const int b = blockIdx.y;
    const short* base = h2 + (long)c8 * 8;
    float mx[8];
#pragma unroll
    for (int j = 0; j < 8; ++j) mx[j] = -INFINITY;
    const int i0 = bptr[b], i1 = bptr[b + 1];
    for (int i = i0; i < i1; ++i) {
        s16x8 v = *(const s16x8*)(base + (long)i * Wp);
#pragma unroll
        for (int j = 0; j < 8; ++j) mx[j] = fmaxf(mx[j], b2f(v[j]));
    }
#pragma unroll
    for (int j = 0; j < 8; ++j) g[(long)b * Wp + c8 * 8 + j] = mx[j];
}

// ---------------- linear1 split-K ----------------
__global__ __launch_bounds__(256)
void k_lin1_part(const float* __restrict__ g, const float* __restrict__ Wl1,
                 float* __restrict__ part) {
    __shared__ float gs[64][65];
    __shared__ float Ws[64][64];
    const int tid = threadIdx.x;
    const int jc = blockIdx.x * 64;
    const int k0 = blockIdx.y * LCHUNK;
    const int k1 = min(6000, k0 + LCHUNK);
    const int r = tid & 63;
    const int jb = (tid >> 6) * 16;
    float acc[16] = {};
    for (int kc = k0; kc < k1; kc += 64) {
#pragma unroll
        for (int p = 0; p < 16; ++p) {
            int el = p * 256 + tid;
            int rr = el >> 6, kk = el & 63;
            gs[rr][kk] = (kc + kk < k1) ? g[rr * K2 + kc + kk] : 0.f;
            Ws[rr][kk] = (kc + rr < k1 && jc + kk < 3000)
                         ? Wl1[(long)(kc + rr) * 3000 + jc + kk] : 0.f;
        }
        __syncthreads();
#pragma unroll
        for (int k = 0; k < 64; ++k) {
            float a = gs[r][k];
#pragma unroll
            for (int jj = 0; jj < 16; ++jj)
                acc[jj] += a * Ws[k][jb + jj];
        }
        __syncthreads();
    }
    float* prow = part + ((long)blockIdx.y * 64 + r) * L1p + jc + jb;
#pragma unroll
    for (int jj = 0; jj < 16; ++jj) prow[jj] = acc[jj];
}

__global__ __launch_bounds__(256)
void k_lin1_red(const float* __restrict__ part, const float* __restrict__ bl1,
                float* __restrict__ g1) {
    int idx = blockIdx.x * 256 + threadIdx.x;
    if (idx >= 64 * 3000) return;
    int r = idx / 3000;
    int c = idx - r * 3000;
    float s = bl1[c];
#pragma unroll
    for (int p = 0; p < NCH; ++p)
        s += part[((long)p * 64 + r) * L1p + c];
    g1[r * L1p + c] = LRELU(s);
}

// ---------------- linear2 ----------------
__global__ __launch_bounds__(256)
void k_lin2(const float* __restrict__ g1, const float* __restrict__ Wl2,
            const float* __restrict__ bl2, float* __restrict__ out) {
    const int r = blockIdx.x;
    const int tid = threadIdx.x;
    float a0 = 0, a1 = 0, a2 = 0, a3 = 0;
    for (int k = tid; k < 3000; k += 256) {
        float gv = g1[r * L1p + k];
        const float* w = Wl2 + (long)k * 4;
        a0 += gv * w[0]; a1 += gv * w[1]; a2 += gv * w[2]; a3 += gv * w[3];
    }
    __shared__ float red[256][4];
    red[tid][0] = a0; red[tid][1] = a1; red[tid][2] = a2; red[tid][3] = a3;
    __syncthreads();
    for (int s = 128; s > 0; s >>= 1) {
        if (tid < s) {
            red[tid][0] += red[tid + s][0]; red[tid][1] += red[tid + s][1];
            red[tid][2] += red[tid + s][2]; red[tid][3] += red[tid + s][3];
        }
        __syncthreads();
    }
    if (tid < 4) {
        float v = red[0][tid] + bl2[tid];
        out[r * 4 + tid] = LRELU(v);
    }
}

// ---------------- launch ----------------
extern "C" void kernel_launch(void* const* d_in, const int* in_sizes, int n_in,
                              void* d_out, int out_size, void* d_ws, size_t ws_size,
                              hipStream_t stream)
{
    const int*   x     = (const int*)d_in[0];
    const int*   ei    = (const int*)d_in[1];
    const int*   batch = (const int*)d_in[2];
    const float* emb   = (const float*)d_in[3];
    const float* W1    = (const float*)d_in[4];
    const float* b1    = (const float*)d_in[5];
    const float* W2    = (const float*)d_in[6];
    const float* b2    = (const float*)d_in[7];
    const float* Wl1   = (const float*)d_in[8];
    const float* bl1   = (const float*)d_in[9];
    const float* Wl2   = (const float*)d_in[10];
    const float* bl2   = (const float*)d_in[11];
    float* out = (float*)d_out;

    const int* esrc = ei;
    const int* edst = ei + Ee;

    const size_t MiB = 1ull << 20;
    char* W = (char*)d_ws;
    short* h0b  = (short*)(W + 0);          // [8192,4096] bf16, 64 MiB
    short* Ah0b = (short*)(W + 64 * MiB);   // [8192,4096] bf16, 64 MiB
    short* W2t  = (short*)(W + 96 * MiB);   // [6144,6144] bf16, 72 MiB (after GEMM1)
    short* W1t  = (short*)(W + 128 * MiB);  // [6144,4096] bf16, 48 MiB
    short* h1b  = (short*)(W + 176 * MiB);  // [8192,6144] bf16, 96 MiB
    short* Ah1b = (short*)(W + 0);          // [8192,6144] bf16, 96 MiB (after GEMM1)
    short* h2b  = h1b;                      // reuse
    float* part = (float*)(W + 0);          // [24][64][3072] f32 (after pool)
    char* S = W + 272 * MiB;
    int*   indeg  = (int*)(S);
    float* dinv   = (float*)(S + 32 * 1024);
    int*   rowptr = (int*)(S + 64 * 1024);
    int*   fillc  = (int*)(S + 96 * 1024);
    int*   csr    = (int*)(S + 128 * 1024);
    int*   bptr   = (int*)(S + 256 * 1024);
    float* g      = (float*)(S + 320 * 1024);
    float* g1     = (float*)(S + 320 * 1024 + 2 * MiB);

    hipMemsetAsync(indeg, 0, Nn * sizeof(int), stream);
    hipMemsetAsync(fillc, 0, Nn * sizeof(int), stream);

    k_gather<<<Nn, 256, 0, stream>>>(x, emb, h0b, K1);
    k_deg<<<(Ee + 255) / 256, 256, 0, stream>>>(edst, indeg);
    k_scan<<<1, 1024, 0, stream>>>(indeg, rowptr, dinv, Nn);
    k_fill<<<(Ee + 255) / 256, 256, 0, stream>>>(esrc, edst, rowptr, fillc, csr);

    const int nbx = K2 / GBN;               // 24
    const int nwg = nbx * (Mp / GBM);       // 24*32 = 768, % 8 == 0

    k_agg<2><<<Nn, 256, 0, stream>>>(h0b, Ah0b, dinv, rowptr, csr, K1);
    k_transpose<<<dim3(K1 / 32, K2 / 32), 256, 0, stream>>>(W1, W1t, 4000, 6000, K1, K2);
    k_gemm8w<<<nwg, 512, 0, stream>>>(Ah0b, W1t, h1b, b1, K1, K1L, K2, 6000, nbx);

    k_transpose<<<dim3(K2 / 32, K2 / 32), 256, 0, stream>>>(W2, W2t, 6000, 6000, K2, K2);
    k_agg<3><<<Nn, 256, 0, stream>>>(h1b, Ah1b, dinv, rowptr, csr, K2);
    k_gemm8w<<<nwg, 512, 0, stream>>>(Ah1b, W2t, h2b, b2, K2, K2L, K2, 6000, nbx);

    k_bptr<<<(Nn + 255) / 256, 256, 0, stream>>>(batch, bptr);
    k_pool<<<dim3(K2 / 2048, Bb), 256, 0, stream>>>(h2b, bptr, g, K2);
    k_lin1_part<<<dim3(L1p / 64, NCH), 256, 0, stream>>>(g, Wl1, part);
    k_lin1_red<<<(64 * 3000 + 255) / 256, 256, 0, stream>>>(part, bl1, g1);
    k_lin2<<<Bb, 256, 0, stream>>>(g1, Wl2, bl2, out);
}